// Round 1
// baseline (311.787 us; speedup 1.0000x reference)
//
#include <hip/hip_runtime.h>

#define V 5003
#define NROWS 8192      // 64*128
#define BB 64
#define SS 200
#define DD 128
#define TAU 0.07f
#define LOG2E 1.4426950408889634f
#define LN2 0.6931471805599453f
#define NEG_BIG -3.0e38f

// ws layout: [0]=focal_sum [1]=valid_count [2]=contrastive_sum [3]=pairs

__device__ __forceinline__ void online_upd(float& m, float& s, float x) {
    float nm = fmaxf(m, x);
    s = s * exp2f((m - nm) * LOG2E) + exp2f((x - nm) * LOG2E);
    m = nm;
}

__device__ __forceinline__ void online_merge(float& m, float& s, float mo, float so) {
    float nm = fmaxf(m, mo);
    s = s * exp2f((m - nm) * LOG2E) + so * exp2f((mo - nm) * LOG2E);
    m = nm;
}

__global__ void init_ws_kernel(float* ws) {
    if (threadIdx.x < 4) ws[threadIdx.x] = 0.0f;
}

__global__ __launch_bounds__(256) void fused_loss_kernel(
    const float* __restrict__ logits,   // [64,128,5003]
    const int*   __restrict__ targets,  // [64,128]
    const int*   __restrict__ mmask,    // [64,128]
    const float* __restrict__ emb,      // [64,200,128]
    const int*   __restrict__ pids,     // [64,200]
    const int*   __restrict__ amask,    // [64,200]
    float* __restrict__ ws)
{
    const int tid  = threadIdx.x;
    const int lane = tid & 63;
    const int wave = tid >> 6;

    // ---- shared memory (both paths; total ~5 KB) ----
    __shared__ float fl_sh[4];
    __shared__ int   vc_sh[4];
    __shared__ __align__(16) float anchors[8][DD];
    __shared__ float possim[8];
    __shared__ unsigned char validb[SS];
    __shared__ short poslist[16];
    __shared__ int   n_sh;
    __shared__ int   nanch_sh;
    __shared__ float red[4][8];
    __shared__ float contrib_sh[8];

    if (blockIdx.x < 2048) {
        // ================= FOCAL: one wave per row =================
        const int r = blockIdx.x * 4 + wave;
        const float* row = logits + (size_t)r * V;

        float m0=NEG_BIG, s0=0.f, m1=NEG_BIG, s1=0.f;
        float m2=NEG_BIG, s2=0.f, m3=NEG_BIG, s3=0.f;

        int k = lane;
        for (int i = 0; i < 19; ++i, k += 256) {
            float x0 = row[k];
            float x1 = row[k + 64];
            float x2 = row[k + 128];
            float x3 = row[k + 192];
            online_upd(m0, s0, x0);
            online_upd(m1, s1, x1);
            online_upd(m2, s2, x2);
            online_upd(m3, s3, x3);
        }
        // tail: k = 4864 + lane; V = 5003
        {
            float xa = row[k];        // 4864+lane <= 4927
            float xb = row[k + 64];   // 4928+lane <= 4991
            online_upd(m0, s0, xa);
            online_upd(m1, s1, xb);
            if (k + 128 < V)          // lanes 0..10
                online_upd(m2, s2, row[k + 128]);
        }
        online_merge(m0, s0, m1, s1);
        online_merge(m2, s2, m3, s3);
        online_merge(m0, s0, m2, s2);
        for (int off = 32; off; off >>= 1) {
            float mo = __shfl_xor(m0, off, 64);
            float so = __shfl_xor(s0, off, 64);
            online_merge(m0, s0, mo, so);
        }

        if (lane == 0) {
            int t  = targets[r];
            int mk = mmask[r];
            bool valid = (t != -100) && (mk == 1);
            int tc = t < 0 ? 0 : t;
            float xt  = row[tc];
            float lse = m0 + log2f(s0) * LN2;
            float lp  = xt - lse;           // log p_t
            float pt  = exp2f(lp * LOG2E);
            float om  = 1.0f - pt;
            fl_sh[wave] = valid ? (om * om * (-lp)) : 0.0f;
            vc_sh[wave] = valid ? 1 : 0;
        }
        __syncthreads();
        if (tid == 0) {
            float fs = fl_sh[0] + fl_sh[1] + fl_sh[2] + fl_sh[3];
            int   vc = vc_sh[0] + vc_sh[1] + vc_sh[2] + vc_sh[3];
            atomicAdd(&ws[0], fs);
            atomicAdd(&ws[1], (float)vc);
        }
    } else {
        // ================= CONTRASTIVE: one block per batch =================
        const int b = blockIdx.x - 2048;

        if (tid == 0) n_sh = 0;
        __syncthreads();

        if (tid < SS) {
            int idx = b * SS + tid;
            bool v = (amask[idx] == 1) && (pids[idx] > 0);
            validb[tid] = v ? 1 : 0;
            if (v) atomicAdd(&n_sh, 1);
        }
        __syncthreads();

        if (tid == 0) {
            int cnt = 0;
            for (int s = 0; s < SS && cnt < 16; ++s)
                if (validb[s]) poslist[cnt++] = (short)s;
            for (; cnt < 16; ++cnt) poslist[cnt] = (short)(SS - 1);
            int n  = n_sh;
            int na = n / 2;
            if (na > 8) na = 8;
            nanch_sh = na;
        }
        __syncthreads();
        const int n_anch = nanch_sh;

        // normalize anchors into LDS; compute pos_sim. wave w: anchors w and w+4
        const float2* embb = (const float2*)(emb + (size_t)b * SS * DD);
        for (int jj = 0; jj < 2; ++jj) {
            int j = wave + jj * 4;
            if (j < n_anch) {
                int ai = poslist[j];
                int pi = poslist[n_anch + j];
                float2 a2 = embb[ai * 64 + lane];
                float2 p2 = embb[pi * 64 + lane];
                float na_ = a2.x * a2.x + a2.y * a2.y;
                float np_ = p2.x * p2.x + p2.y * p2.y;
                float dp  = a2.x * p2.x + a2.y * p2.y;
                for (int off = 32; off; off >>= 1) {
                    na_ += __shfl_xor(na_, off, 64);
                    np_ += __shfl_xor(np_, off, 64);
                    dp  += __shfl_xor(dp,  off, 64);
                }
                float rna = 1.0f / fmaxf(sqrtf(na_), 1e-12f);
                float rnp = 1.0f / fmaxf(sqrtf(np_), 1e-12f);
                anchors[j][2 * lane]     = a2.x * rna;
                anchors[j][2 * lane + 1] = a2.y * rna;
                if (lane == 0) possim[j] = dp * rna * rnp * (1.0f / TAU);
            } else {
                anchors[j][2 * lane]     = 0.0f;
                anchors[j][2 * lane + 1] = 0.0f;
                if (lane == 0) possim[j] = 0.0f;
            }
        }
        __syncthreads();

        // negatives: 4 neighbor batches x 200 positions = 800, one per thread slot
        float part[8];
        #pragma unroll
        for (int j = 0; j < 8; ++j) part[j] = 0.0f;

        for (int i = 0; i < 4; ++i) {
            int g = tid + i * 256;
            if (g < 4 * SS) {
                int ol = g / SS;                 // 0..3
                int s  = g - ol * SS;
                int o  = (ol >= b) ? ol + 1 : ol;  // first-4-others rule
                int idx = o * SS + s;
                if (amask[idx] == 1 && pids[idx] > 0) {
                    const float4* nb = (const float4*)(emb + (size_t)idx * DD);
                    float acc[8];
                    float n2 = 0.0f;
                    #pragma unroll
                    for (int j = 0; j < 8; ++j) acc[j] = 0.0f;
                    #pragma unroll 8
                    for (int c = 0; c < DD / 4; ++c) {
                        float4 x = nb[c];
                        n2 += x.x * x.x + x.y * x.y + x.z * x.z + x.w * x.w;
                        #pragma unroll
                        for (int j = 0; j < 8; ++j) {
                            float4 a = ((const float4*)anchors[j])[c];
                            acc[j] += a.x * x.x + a.y * x.y + a.z * x.z + a.w * x.w;
                        }
                    }
                    float rn = 1.0f / fmaxf(sqrtf(n2), 1e-12f);
                    #pragma unroll
                    for (int j = 0; j < 8; ++j) {
                        float sim = acc[j] * rn * (1.0f / TAU);
                        part[j] += exp2f(sim * LOG2E);   // |sim|<=14.3: no overflow
                    }
                }
            }
        }

        // block-reduce the 8 partial exp-sums
        #pragma unroll
        for (int j = 0; j < 8; ++j)
            for (int off = 32; off; off >>= 1)
                part[j] += __shfl_xor(part[j], off, 64);
        if (lane == 0) {
            #pragma unroll
            for (int j = 0; j < 8; ++j) red[wave][j] = part[j];
        }
        __syncthreads();

        if (tid < 8) {
            int j = tid;
            float ps = possim[j];
            float S  = exp2f(ps * LOG2E) + red[0][j] + red[1][j] + red[2][j] + red[3][j];
            float lse = log2f(S) * LN2;
            contrib_sh[j] = (j < n_anch) ? (lse - ps) : 0.0f;
        }
        __syncthreads();
        if (tid == 0) {
            float lb = 0.0f;
            for (int j = 0; j < 8; ++j) lb += contrib_sh[j];
            atomicAdd(&ws[2], lb);
            atomicAdd(&ws[3], (float)n_anch);
        }
    }
}

__global__ void finalize_kernel(const float* __restrict__ ws, float* __restrict__ out) {
    if (threadIdx.x == 0) {
        float fs = ws[0], vc = ws[1], cs = ws[2], pr = ws[3];
        float focal = vc > 0.0f ? fs / vc : 0.0f;
        float contr = pr > 0.0f ? cs / pr : 0.0f;
        out[0] = 0.6f * focal + 0.2f * contr;
    }
}

extern "C" void kernel_launch(void* const* d_in, const int* in_sizes, int n_in,
                              void* d_out, int out_size, void* d_ws, size_t ws_size,
                              hipStream_t stream) {
    const float* logits  = (const float*)d_in[0];
    const int*   targets = (const int*)d_in[1];
    const int*   mmask   = (const int*)d_in[2];
    const float* emb     = (const float*)d_in[3];
    const int*   pids    = (const int*)d_in[4];
    const int*   amask   = (const int*)d_in[5];
    float* out = (float*)d_out;
    float* ws  = (float*)d_ws;

    hipLaunchKernelGGL(init_ws_kernel, dim3(1), dim3(64), 0, stream, ws);
    hipLaunchKernelGGL(fused_loss_kernel, dim3(2048 + 64), dim3(256), 0, stream,
                       logits, targets, mmask, emb, pids, amask, ws);
    hipLaunchKernelGGL(finalize_kernel, dim3(1), dim3(64), 0, stream, ws, out);
}